// Round 3
// baseline (556.340 us; speedup 1.0000x reference)
//
#include <hip/hip_runtime.h>
#include <math.h>
#include <stdint.h>

#define BB 8
#define NN 16384
#define CC 80
#define TT 100
#define CAP 1024
#define BAND_LO 0.97f

typedef unsigned int u32;
typedef unsigned long long u64;

__device__ __forceinline__ void argmax_f_i(float& v, int& i) {
#pragma unroll
  for (int d = 1; d < 64; d <<= 1) {
    float ov = __shfl_xor(v, d);
    int   oi = __shfl_xor(i, d);
    if (ov > v || (ov == v && oi < i)) { v = ov; i = oi; }
  }
}

// ---------- K1: fused threshold + band gather over scores (B,N,C) ----------
// Pushes keys ((fbits(v)<<32) | ~n) for v >= BAND_LO into per-(b,c) lists.
__global__ __launch_bounds__(256) void gather_kernel(const float* __restrict__ scores,
                                                     u64* __restrict__ cand,
                                                     int* __restrict__ cnt) {
  const float4* s4 = (const float4*)scores;
  const size_t total4 = (size_t)BB * NN * CC / 4;   // 2,621,440
  size_t stride = (size_t)gridDim.x * blockDim.x;
  for (size_t i4 = (size_t)blockIdx.x * blockDim.x + threadIdx.x; i4 < total4; i4 += stride) {
    float4 q = s4[i4];
    size_t base = i4 * 4;
#pragma unroll
    for (int e = 0; e < 4; ++e) {
      float v = (e == 0) ? q.x : (e == 1) ? q.y : (e == 2) ? q.z : q.w;
      if (v >= BAND_LO) {
        size_t idx = base + e;
        int c = (int)(idx % CC);
        size_t bn = idx / CC;          // b*NN + n
        int b = (int)(bn / NN);
        int n = (int)(bn % NN);
        int bc = b * CC + c;
        int s = atomicAdd(&cnt[bc], 1);
        if (s < CAP) cand[(size_t)bc * CAP + s] = ((u64)__float_as_uint(v) << 32) | (u32)(~(u32)n);
      }
    }
  }
}

// ---------- K2: per-(b,c) sort + serial greedy (256 threads; greedy on wave 0) ----------
__global__ __launch_bounds__(256) void nms_kernel(const float* __restrict__ boxes,
                                                  const float* __restrict__ scores,
                                                  const u64* __restrict__ cand,
                                                  const int* __restrict__ cnt,
                                                  float* __restrict__ det_score,
                                                  float* __restrict__ det_box) {
  __shared__ u64 keys[CAP];
  __shared__ float4 bxs[CAP];
  __shared__ int cnt_s, nsel_s;

  int bc = blockIdx.x;
  int b = bc / CC, c = bc % CC;
  int tid = threadIdx.x;
  const float* bsrc = boxes + (size_t)b * NN * 4;
  float* dsc = det_score + (size_t)bc * TT;
  float4* dbx = (float4*)det_box + (size_t)bc * TT;

  int cnt0 = cnt[bc];
  bool pre_ok = (cnt0 <= CAP);

  // wave-0 greedy state
  int nsel = 0;
  float4 sel0 = make_float4(0.f, 0.f, 0.f, 0.f);
  float4 sel1 = make_float4(0.f, 0.f, 0.f, 0.f);
  float sa0 = 0.f, sa1 = 0.f;

  float lo = BAND_LO, hi = INFINITY;
  bool first = true;
  if (tid == 0) nsel_s = 0;
  __syncthreads();

  for (;;) {
    // ---- build candidate list for band [lo, hi)
    int m;
    if (first && pre_ok) {
      m = cnt0;
      for (int s = tid; s < m; s += 256) keys[s] = cand[(size_t)bc * CAP + s];
    } else {
      float band_lo = lo;
      for (int tries = 0;; ++tries) {
        if (tid == 0) cnt_s = 0;
        __syncthreads();
        for (int n = tid; n < NN; n += 256) {
          float v = scores[((size_t)b * NN + n) * CC + c];
          if (v > 0.3f && v >= band_lo && v < hi) {
            int s = atomicAdd(&cnt_s, 1);
            if (s < CAP) keys[s] = ((u64)__float_as_uint(v) << 32) | (u32)(~(u32)n);
          }
        }
        __syncthreads();
        if (cnt_s <= CAP || tries >= 24) break;
        float hi_eff = (hi > 1.0f) ? 1.0f : hi;
        band_lo = 0.5f * (band_lo + hi_eff);
        __syncthreads();
      }
      m = (cnt_s < CAP) ? cnt_s : CAP;
      lo = band_lo;   // consumed band is [band_lo, hi)
    }
    first = false;

    if (m > 0) {
      // pad to power of two
      int n2 = 64;
      while (n2 < m) n2 <<= 1;
      for (int s = m + tid; s < n2; s += 256) keys[s] = 0ull;
      __syncthreads();
      // bitonic sort descending (score desc, idx asc via ~idx)
      for (int k = 2; k <= n2; k <<= 1) {
        for (int j = k >> 1; j > 0; j >>= 1) {
          for (int i = tid; i < n2; i += 256) {
            int ixj = i ^ j;
            if (ixj > i) {
              u64 a = keys[i], d2 = keys[ixj];
              bool up = ((i & k) == 0);
              if (up ? (a < d2) : (a > d2)) { keys[i] = d2; keys[ixj] = a; }
            }
          }
          __syncthreads();
        }
      }
      // prefetch candidate boxes in sorted order
      for (int s = tid; s < m; s += 256) {
        u32 g = ~(u32)keys[s];
        bxs[s] = *(const float4*)(bsrc + (size_t)g * 4);
      }
      __syncthreads();

      // ---- serial greedy on wave 0; lane l caches selected slots l, 64+l
      if (tid < 64) {
        int lane = tid;
        u64 key_n = keys[0];
        float4 bx_n = bxs[0];
        for (int s = 0; s < m && nsel < TT; ++s) {
          u64 key = key_n; float4 bx = bx_n;
          if (s + 1 < m) { key_n = keys[s + 1]; bx_n = bxs[s + 1]; }
          float v = __uint_as_float((u32)(key >> 32));
          float by1 = bx.x, bx1v = bx.y, by2 = bx.z, bx2v = bx.w;
          float areac = fmaxf(by2 - by1, 0.f) * fmaxf(bx2v - bx1v, 0.f);
          int sup = 0;
          if (lane < nsel) {
            float yy1 = fmaxf(sel0.x, by1), xx1 = fmaxf(sel0.y, bx1v);
            float yy2 = fminf(sel0.z, by2), xx2 = fminf(sel0.w, bx2v);
            float inter = fmaxf(yy2 - yy1, 0.f) * fmaxf(xx2 - xx1, 0.f);
            float uni = sa0 + areac - inter;
            if (inter / fmaxf(uni, 1e-9f) >= 0.5f) sup = 1;
          }
          if (64 + lane < nsel) {
            float yy1 = fmaxf(sel1.x, by1), xx1 = fmaxf(sel1.y, bx1v);
            float yy2 = fminf(sel1.z, by2), xx2 = fminf(sel1.w, bx2v);
            float inter = fmaxf(yy2 - yy1, 0.f) * fmaxf(xx2 - xx1, 0.f);
            float uni = sa1 + areac - inter;
            if (inter / fmaxf(uni, 1e-9f) >= 0.5f) sup = 1;
          }
          if (!__any(sup)) {
            if (nsel == lane)      { sel0 = bx; sa0 = areac; }
            if (nsel == 64 + lane) { sel1 = bx; sa1 = areac; }
            if (lane == 0) { dsc[nsel] = v; dbx[nsel] = bx; }
            ++nsel;
          }
        }
        if (lane == 0) nsel_s = nsel;
      }
      __syncthreads();
    }

    int ns = nsel_s;
    if (ns >= TT || lo <= 0.0f) break;
    hi = lo;
    float nlo = lo - 0.03f;
    lo = (nlo <= 0.31f) ? 0.0f : nlo;
    __syncthreads();
  }
  // sentinel for empty slots
  for (int t = nsel_s + tid; t < TT; t += 256) dsc[t] = -INFINITY;
}

// ---------- K3: per-batch 80-way merge top-100 (lists sorted desc; j=100c+t monotone in c) ----------
__global__ __launch_bounds__(64) void topk_merge(const float* __restrict__ det_score,
                                                 const float* __restrict__ det_box,
                                                 float* __restrict__ out) {
  __shared__ float ds[CC * TT];
  __shared__ int widx[TT];
  __shared__ float wval[TT];
  int b = blockIdx.x, lane = threadIdx.x;
  for (int i = lane; i < CC * TT; i += 64) ds[i] = det_score[(size_t)b * CC * TT + i];
  __builtin_amdgcn_wave_barrier();

  int h0 = 0, h1 = 0;
  int c1 = 64 + lane;
  bool has1 = lane < (CC - 64);
  float hv0 = ds[lane * TT];
  float hv1 = has1 ? ds[c1 * TT] : -INFINITY;

  for (int r = 0; r < TT; ++r) {
    float v = hv0; int cw = lane;
    if (has1 && hv1 > hv0) { v = hv1; cw = c1; }
    argmax_f_i(v, cw);                 // tie -> smaller class -> smaller global j
    if (cw == lane) {
      widx[r] = cw * TT + h0; wval[r] = v;
      ++h0; hv0 = (h0 < TT) ? ds[lane * TT + h0] : -INFINITY;
    } else if (has1 && cw == c1) {
      widx[r] = cw * TT + h1; wval[r] = v;
      ++h1; hv1 = (h1 < TT) ? ds[c1 * TT + h1] : -INFINITY;
    }
    __builtin_amdgcn_wave_barrier();
  }

  float* ob = out + (size_t)b * TT * 4;            // [0,3200)
  float* os = out + BB * TT * 4 + (size_t)b * TT;  // [3200,4000)
  float* ol = out + BB * TT * 5 + (size_t)b * TT;  // [4000,4800)
  int vc = 0;
  for (int t = lane; t < TT; t += 64) {
    float v = wval[t]; int wi = widx[t];
    bool valid = (v != -INFINITY);
    float4 bx = make_float4(0.f, 0.f, 0.f, 0.f);
    if (valid) bx = *(const float4*)(det_box + ((size_t)b * CC * TT + wi) * 4);
    ((float4*)ob)[t] = bx;
    os[t] = valid ? v : 0.0f;
    ol[t] = valid ? (float)(wi / TT) : 0.0f;
    vc += valid ? 1 : 0;
  }
#pragma unroll
  for (int d = 1; d < 64; d <<= 1) vc += __shfl_xor(vc, d);
  if (lane == 0) out[BB * TT * 5 + BB * TT + b] = (float)vc;
}

// ---------- launch ----------
extern "C" void kernel_launch(void* const* d_in, const int* in_sizes, int n_in,
                              void* d_out, int out_size, void* d_ws, size_t ws_size,
                              hipStream_t stream) {
  const float* boxes  = (const float*)d_in[0];   // (8,16384,4)
  const float* scores = (const float*)d_in[1];   // (8,16384,80)
  float* out = (float*)d_out;                    // 4808 floats

  char* ws = (char*)d_ws;
  // layout (16B aligned):
  u64*   cand      = (u64*)ws;                               // 640*1024*8 = 5,242,880
  float* det_box   = (float*)(ws + 5242880);                 // 640*100*16 = 1,024,000
  float* det_score = (float*)(ws + 5242880 + 1024000);       // 640*100*4  =   256,000
  int*   cnt       = (int*)(ws + 5242880 + 1024000 + 256000);// 640*4      =     2,560

  hipMemsetAsync(cnt, 0, BB * CC * sizeof(int), stream);
  gather_kernel<<<2560, 256, 0, stream>>>(scores, cand, cnt);
  nms_kernel<<<BB * CC, 256, 0, stream>>>(boxes, scores, cand, cnt, det_score, det_box);
  topk_merge<<<BB, 64, 0, stream>>>(det_score, det_box, out);
}

// Round 4
// 273.760 us; speedup vs baseline: 2.0322x; 2.0322x over previous
//
#include <hip/hip_runtime.h>
#include <math.h>
#include <stdint.h>

#define BB 8
#define NN 16384
#define CC 80
#define TT 100
#define CAP 1024
#define BAND_LO 0.97f

typedef unsigned int u32;
typedef unsigned long long u64;

__device__ __forceinline__ void argmax_f_i(float& v, int& i) {
#pragma unroll
  for (int d = 1; d < 64; d <<= 1) {
    float ov = __shfl_xor(v, d);
    int   oi = __shfl_xor(i, d);
    if (ov > v || (ov == v && oi < i)) { v = ov; i = oi; }
  }
}

// ---------- K1: fused gather + sort + greedy NMS, one block per (b,c) ----------
__global__ __launch_bounds__(256) void nms_fused(const float* __restrict__ boxes,
                                                 const float* __restrict__ scores,
                                                 float* __restrict__ det_score,
                                                 float* __restrict__ det_box) {
  __shared__ u64 keys[CAP];
  __shared__ float4 bxs[CAP];
  __shared__ int cnt_s, nsel_s;

  int bc = blockIdx.x;
  int b = bc / CC, c = bc % CC;
  int g = c >> 2, e = c & 3;          // float4 quad index + component (block-uniform)
  int tid = threadIdx.x;
  int lane = tid & 63;
  const float4* s4 = (const float4*)scores;
  const float* bsrc = boxes + (size_t)b * NN * 4;
  float* dsc = det_score + (size_t)bc * TT;
  float4* dbx = (float4*)det_box + (size_t)bc * TT;

  if (tid == 0) { cnt_s = 0; nsel_s = 0; }
  __syncthreads();

  // ---- phase 1: scan column via quad loads, ballot-compact band [BAND_LO, inf) into LDS
  size_t rowbase = (size_t)b * NN;
  float4 q = s4[(rowbase + tid) * (CC / 4) + g];
#pragma unroll 1
  for (int k = 0; k < 64; ++k) {
    int kn = (k < 63) ? k + 1 : 63;
    float4 qn = s4[(rowbase + (size_t)kn * 256 + tid) * (CC / 4) + g];  // prefetch next
    float v = (e == 0) ? q.x : (e == 1) ? q.y : (e == 2) ? q.z : q.w;
    int n = k * 256 + tid;
    u64 mask = __ballot(v >= BAND_LO);
    if (mask) {
      int leader = __ffsll(mask) - 1;
      int base = 0;
      if (lane == leader) base = atomicAdd(&cnt_s, __popcll(mask));
      base = __shfl(base, leader);
      if (v >= BAND_LO) {
        int pos = base + __popcll(mask & ((1ull << lane) - 1ull));
        if (pos < CAP) keys[pos] = ((u64)__float_as_uint(v) << 32) | (u32)(~(u32)n);
      }
    }
    q = qn;
  }
  __syncthreads();
  int cnt0 = cnt_s;
  bool pre_ok = (cnt0 <= CAP);        // overflow (never on this dist) -> exact fallback rescan

  // wave-0 greedy state
  int nsel = 0;
  float4 sel0 = make_float4(0.f, 0.f, 0.f, 0.f);
  float4 sel1 = make_float4(0.f, 0.f, 0.f, 0.f);
  float sa0 = 0.f, sa1 = 0.f;

  float lo = BAND_LO, hi = INFINITY;
  bool first = true;

  for (;;) {
    // ---- build candidate list for band [lo, hi)
    int m;
    if (first && pre_ok) {
      m = cnt0;                       // already in LDS keys[0..m)
    } else {
      float band_lo = lo;
      for (int tries = 0;; ++tries) {
        if (tid == 0) cnt_s = 0;
        __syncthreads();
        for (int n = tid; n < NN; n += 256) {
          float v = scores[((size_t)b * NN + n) * CC + c];
          if (v > 0.3f && v >= band_lo && v < hi) {
            int s = atomicAdd(&cnt_s, 1);
            if (s < CAP) keys[s] = ((u64)__float_as_uint(v) << 32) | (u32)(~(u32)n);
          }
        }
        __syncthreads();
        if (cnt_s <= CAP || tries >= 24) break;
        float hi_eff = (hi > 1.0f) ? 1.0f : hi;
        band_lo = 0.5f * (band_lo + hi_eff);
        __syncthreads();
      }
      m = (cnt_s < CAP) ? cnt_s : CAP;
      lo = band_lo;                   // consumed band is [band_lo, hi)
    }
    first = false;

    if (m > 0) {
      // pad to power of two
      int n2 = 64;
      while (n2 < m) n2 <<= 1;
      for (int s = m + tid; s < n2; s += 256) keys[s] = 0ull;
      __syncthreads();
      // bitonic sort descending (score desc, idx asc via ~idx)
      for (int k = 2; k <= n2; k <<= 1) {
        for (int j = k >> 1; j > 0; j >>= 1) {
          for (int i = tid; i < n2; i += 256) {
            int ixj = i ^ j;
            if (ixj > i) {
              u64 a = keys[i], d2 = keys[ixj];
              bool up = ((i & k) == 0);
              if (up ? (a < d2) : (a > d2)) { keys[i] = d2; keys[ixj] = a; }
            }
          }
          __syncthreads();
        }
      }
      // prefetch candidate boxes in sorted order
      for (int s = tid; s < m; s += 256) {
        u32 gidx = ~(u32)keys[s];
        bxs[s] = *(const float4*)(bsrc + (size_t)gidx * 4);
      }
      __syncthreads();

      // ---- serial greedy on wave 0; lane l caches selected slots l, 64+l in registers
      if (tid < 64) {
        u64 key_n = keys[0];
        float4 bx_n = bxs[0];
        for (int s = 0; s < m && nsel < TT; ++s) {
          u64 key = key_n; float4 bx = bx_n;
          if (s + 1 < m) { key_n = keys[s + 1]; bx_n = bxs[s + 1]; }
          float v = __uint_as_float((u32)(key >> 32));
          float by1 = bx.x, bx1v = bx.y, by2 = bx.z, bx2v = bx.w;
          float areac = fmaxf(by2 - by1, 0.f) * fmaxf(bx2v - bx1v, 0.f);
          int sup = 0;
          if (lane < nsel) {
            float yy1 = fmaxf(sel0.x, by1), xx1 = fmaxf(sel0.y, bx1v);
            float yy2 = fminf(sel0.z, by2), xx2 = fminf(sel0.w, bx2v);
            float inter = fmaxf(yy2 - yy1, 0.f) * fmaxf(xx2 - xx1, 0.f);
            float uni = sa0 + areac - inter;
            if (inter / fmaxf(uni, 1e-9f) >= 0.5f) sup = 1;
          }
          if (64 + lane < nsel) {
            float yy1 = fmaxf(sel1.x, by1), xx1 = fmaxf(sel1.y, bx1v);
            float yy2 = fminf(sel1.z, by2), xx2 = fminf(sel1.w, bx2v);
            float inter = fmaxf(yy2 - yy1, 0.f) * fmaxf(xx2 - xx1, 0.f);
            float uni = sa1 + areac - inter;
            if (inter / fmaxf(uni, 1e-9f) >= 0.5f) sup = 1;
          }
          if (!__any(sup)) {
            if (nsel == lane)      { sel0 = bx; sa0 = areac; }
            if (nsel == 64 + lane) { sel1 = bx; sa1 = areac; }
            if (lane == 0) { dsc[nsel] = v; dbx[nsel] = bx; }
            ++nsel;
          }
        }
        if (lane == 0) nsel_s = nsel;
      }
      __syncthreads();
    }

    int ns = nsel_s;
    if (ns >= TT || lo <= 0.0f) break;
    hi = lo;
    float nlo = lo - 0.03f;
    lo = (nlo <= 0.31f) ? 0.0f : nlo;
    __syncthreads();
  }
  // sentinel for empty slots
  for (int t = nsel_s + tid; t < TT; t += 256) dsc[t] = -INFINITY;
}

// ---------- K2: per-batch 80-way merge top-100 (lists sorted desc; j=100c+t monotone in c) ----------
__global__ __launch_bounds__(64) void topk_merge(const float* __restrict__ det_score,
                                                 const float* __restrict__ det_box,
                                                 float* __restrict__ out) {
  __shared__ float ds[CC * TT];
  __shared__ int widx[TT];
  __shared__ float wval[TT];
  int b = blockIdx.x, lane = threadIdx.x;
  for (int i = lane; i < CC * TT; i += 64) ds[i] = det_score[(size_t)b * CC * TT + i];
  __builtin_amdgcn_wave_barrier();

  int h0 = 0, h1 = 0;
  int c1 = 64 + lane;
  bool has1 = lane < (CC - 64);
  float hv0 = ds[lane * TT];
  float hv1 = has1 ? ds[c1 * TT] : -INFINITY;

  for (int r = 0; r < TT; ++r) {
    float v = hv0; int cw = lane;
    if (has1 && hv1 > hv0) { v = hv1; cw = c1; }
    argmax_f_i(v, cw);                 // tie -> smaller class -> smaller global j
    if (cw == lane) {
      widx[r] = cw * TT + h0; wval[r] = v;
      ++h0; hv0 = (h0 < TT) ? ds[lane * TT + h0] : -INFINITY;
    } else if (has1 && cw == c1) {
      widx[r] = cw * TT + h1; wval[r] = v;
      ++h1; hv1 = (h1 < TT) ? ds[c1 * TT + h1] : -INFINITY;
    }
    __builtin_amdgcn_wave_barrier();
  }

  float* ob = out + (size_t)b * TT * 4;            // [0,3200)
  float* os = out + BB * TT * 4 + (size_t)b * TT;  // [3200,4000)
  float* ol = out + BB * TT * 5 + (size_t)b * TT;  // [4000,4800)
  int vc = 0;
  for (int t = lane; t < TT; t += 64) {
    float v = wval[t]; int wi = widx[t];
    bool valid = (v != -INFINITY);
    float4 bx = make_float4(0.f, 0.f, 0.f, 0.f);
    if (valid) bx = *(const float4*)(det_box + ((size_t)b * CC * TT + wi) * 4);
    ((float4*)ob)[t] = bx;
    os[t] = valid ? v : 0.0f;
    ol[t] = valid ? (float)(wi / TT) : 0.0f;
    vc += valid ? 1 : 0;
  }
#pragma unroll
  for (int d = 1; d < 64; d <<= 1) vc += __shfl_xor(vc, d);
  if (lane == 0) out[BB * TT * 5 + BB * TT + b] = (float)vc;
}

// ---------- launch ----------
extern "C" void kernel_launch(void* const* d_in, const int* in_sizes, int n_in,
                              void* d_out, int out_size, void* d_ws, size_t ws_size,
                              hipStream_t stream) {
  const float* boxes  = (const float*)d_in[0];   // (8,16384,4)
  const float* scores = (const float*)d_in[1];   // (8,16384,80)
  float* out = (float*)d_out;                    // 4808 floats

  char* ws = (char*)d_ws;
  float* det_box   = (float*)ws;                 // 640*100*16 = 1,024,000
  float* det_score = (float*)(ws + 1024000);     // 640*100*4  =   256,000

  nms_fused<<<BB * CC, 256, 0, stream>>>(boxes, scores, det_score, det_box);
  topk_merge<<<BB, 64, 0, stream>>>(det_score, det_box, out);
}

// Round 5
// 203.438 us; speedup vs baseline: 2.7347x; 1.3457x over previous
//
#include <hip/hip_runtime.h>
#include <math.h>
#include <stdint.h>

#define BB 8
#define NN 16384
#define CC 80
#define TT 100
#define CAP 1024
#define BAND_LO 0.97f
#define LCAP 64            // per-block per-class local list cap
#define ROWS 512           // rows per gather block

typedef unsigned int u32;
typedef unsigned long long u64;

// ---------- shared bitonic (descending), 256 threads, n2 = power of two ----------
__device__ __forceinline__ void bitonic_desc(u64* buf, int n2, int tid) {
  for (int k = 2; k <= n2; k <<= 1) {
    for (int j = k >> 1; j > 0; j >>= 1) {
      for (int i = tid; i < n2; i += 256) {
        int ixj = i ^ j;
        if (ixj > i) {
          u64 a = buf[i], d2 = buf[ixj];
          bool up = ((i & k) == 0);
          if (up ? (a < d2) : (a > d2)) { buf[i] = d2; buf[ixj] = a; }
        }
      }
      __syncthreads();
    }
  }
}

// ---------- K1: coalesced one-pass band gather ----------
// block = (b, slice of 512 rows); reads its slice row-major (fully coalesced),
// buckets hits into per-class LDS lists, reserves global space with 80 atomics.
__global__ __launch_bounds__(256) void gather_kernel(const float* __restrict__ scores,
                                                     u64* __restrict__ cand,
                                                     int* __restrict__ cnt,
                                                     int* __restrict__ ov) {
  __shared__ u64 lkeys[CC * LCAP];   // 40 KB
  __shared__ int lcnt[CC];

  int b = blockIdx.x >> 5;
  int slice = blockIdx.x & 31;
  int n0 = slice << 9;               // slice * 512
  int tid = threadIdx.x;

  if (tid < CC) lcnt[tid] = 0;
  __syncthreads();

  const float4* s4 = (const float4*)scores;
  size_t base4 = ((size_t)b * NN + n0) * (CC / 4);
  for (int i = tid; i < ROWS * (CC / 4); i += 256) {
    float4 q = s4[base4 + i];
    int ib = i * 4;
    float vv[4] = {q.x, q.y, q.z, q.w};
#pragma unroll
    for (int e = 0; e < 4; ++e) {
      float v = vv[e];
      if (v >= BAND_LO) {
        int fe = ib + e;
        int c = fe % CC;
        int n = n0 + fe / CC;
        int s = atomicAdd(&lcnt[c], 1);
        if (s < LCAP) lkeys[c * LCAP + s] = ((u64)__float_as_uint(v) << 32) | (u32)(~(u32)n);
      }
    }
  }
  __syncthreads();

  if (tid < CC) {
    int c = tid;
    int lc = lcnt[c];
    int m = (lc < LCAP) ? lc : LCAP;
    int bc = b * CC + c;
    int gb = atomicAdd(&cnt[bc], m);
    if (lc > LCAP) atomicOr(&ov[bc], 1);
    for (int i = 0; i < m; ++i) {
      int pos = gb + i;
      if (pos < CAP) cand[(size_t)bc * CAP + pos] = lkeys[c * LCAP + i];
    }
  }
}

// ---------- K2: per-(b,c) sort + serial greedy (256 threads; greedy on wave 0) ----------
__global__ __launch_bounds__(256) void nms_kernel(const float* __restrict__ boxes,
                                                  const float* __restrict__ scores,
                                                  const u64* __restrict__ cand,
                                                  const int* __restrict__ cnt,
                                                  const int* __restrict__ ov,
                                                  float* __restrict__ det_score,
                                                  float* __restrict__ det_box) {
  __shared__ u64 keys[CAP];
  __shared__ float4 bxs[CAP];
  __shared__ int cnt_s, nsel_s;

  int bc = blockIdx.x;
  int b = bc / CC, c = bc % CC;
  int tid = threadIdx.x;
  int lane = tid & 63;
  const float* bsrc = boxes + (size_t)b * NN * 4;
  float* dsc = det_score + (size_t)bc * TT;
  float4* dbx = (float4*)det_box + (size_t)bc * TT;

  int cnt0 = cnt[bc];
  bool pre_ok = (cnt0 <= CAP) && (ov[bc] == 0);

  // wave-0 greedy state
  int nsel = 0;
  float4 sel0 = make_float4(0.f, 0.f, 0.f, 0.f);
  float4 sel1 = make_float4(0.f, 0.f, 0.f, 0.f);
  float sa0 = 0.f, sa1 = 0.f;

  float lo = BAND_LO, hi = INFINITY;
  bool first = true;
  if (tid == 0) nsel_s = 0;
  __syncthreads();

  for (;;) {
    // ---- build candidate list for band [lo, hi)
    int m;
    if (first && pre_ok) {
      m = cnt0;
      for (int s = tid; s < m; s += 256) keys[s] = cand[(size_t)bc * CAP + s];
      __syncthreads();
    } else {
      float band_lo = lo;
      for (int tries = 0;; ++tries) {
        if (tid == 0) cnt_s = 0;
        __syncthreads();
        for (int n = tid; n < NN; n += 256) {
          float v = scores[((size_t)b * NN + n) * CC + c];
          if (v > 0.3f && v >= band_lo && v < hi) {
            int s = atomicAdd(&cnt_s, 1);
            if (s < CAP) keys[s] = ((u64)__float_as_uint(v) << 32) | (u32)(~(u32)n);
          }
        }
        __syncthreads();
        if (cnt_s <= CAP || tries >= 24) break;
        float hi_eff = (hi > 1.0f) ? 1.0f : hi;
        band_lo = 0.5f * (band_lo + hi_eff);
        __syncthreads();
      }
      m = (cnt_s < CAP) ? cnt_s : CAP;
      lo = band_lo;   // consumed band is [band_lo, hi)
    }
    first = false;

    if (m > 0) {
      // pad to power of two
      int n2 = 64;
      while (n2 < m) n2 <<= 1;
      for (int s = m + tid; s < n2; s += 256) keys[s] = 0ull;
      __syncthreads();
      bitonic_desc(keys, n2, tid);     // (score desc, idx asc via ~idx)
      // prefetch candidate boxes in sorted order
      for (int s = tid; s < m; s += 256) {
        u32 gidx = ~(u32)keys[s];
        bxs[s] = *(const float4*)(bsrc + (size_t)gidx * 4);
      }
      __syncthreads();

      // ---- serial greedy on wave 0; lane l caches selected slots l, 64+l in registers
      if (tid < 64) {
        u64 key_n = keys[0];
        float4 bx_n = bxs[0];
        for (int s = 0; s < m && nsel < TT; ++s) {
          u64 key = key_n; float4 bx = bx_n;
          if (s + 1 < m) { key_n = keys[s + 1]; bx_n = bxs[s + 1]; }
          float v = __uint_as_float((u32)(key >> 32));
          float by1 = bx.x, bx1v = bx.y, by2 = bx.z, bx2v = bx.w;
          float areac = fmaxf(by2 - by1, 0.f) * fmaxf(bx2v - bx1v, 0.f);
          int sup = 0;
          if (lane < nsel) {
            float yy1 = fmaxf(sel0.x, by1), xx1 = fmaxf(sel0.y, bx1v);
            float yy2 = fminf(sel0.z, by2), xx2 = fminf(sel0.w, bx2v);
            float inter = fmaxf(yy2 - yy1, 0.f) * fmaxf(xx2 - xx1, 0.f);
            float uni = sa0 + areac - inter;
            if (inter / fmaxf(uni, 1e-9f) >= 0.5f) sup = 1;
          }
          if (64 + lane < nsel) {
            float yy1 = fmaxf(sel1.x, by1), xx1 = fmaxf(sel1.y, bx1v);
            float yy2 = fminf(sel1.z, by2), xx2 = fminf(sel1.w, bx2v);
            float inter = fmaxf(yy2 - yy1, 0.f) * fmaxf(xx2 - xx1, 0.f);
            float uni = sa1 + areac - inter;
            if (inter / fmaxf(uni, 1e-9f) >= 0.5f) sup = 1;
          }
          if (!__any(sup)) {
            if (nsel == lane)      { sel0 = bx; sa0 = areac; }
            if (nsel == 64 + lane) { sel1 = bx; sa1 = areac; }
            if (lane == 0) { dsc[nsel] = v; dbx[nsel] = bx; }
            ++nsel;
          }
        }
        if (lane == 0) nsel_s = nsel;
      }
      __syncthreads();
    }

    int ns = nsel_s;
    if (ns >= TT || lo <= 0.0f) break;
    hi = lo;
    float nlo = lo - 0.03f;
    lo = (nlo <= 0.31f) ? 0.0f : nlo;
    __syncthreads();
  }
  // sentinel for empty slots
  for (int t = nsel_s + tid; t < TT; t += 256) dsc[t] = -INFINITY;
}

// ---------- K3: per-batch top-100 via threshold-select + small sort ----------
// Per-class det lists are sorted desc by key = (fbits(v)<<32)|~j (j = c*100+t),
// keys distinct -> threshold t100 selects exactly the top-100, ties j-ascending
// exactly like lax.top_k.
__global__ __launch_bounds__(256) void topk_select(const float* __restrict__ det_score,
                                                   const float* __restrict__ det_box,
                                                   float* __restrict__ out) {
  __shared__ u64 kk[CC * TT];     // 64 KB
  __shared__ u64 buf[8192];       // 64 KB (worst-case gather; typical <=512 used)
  __shared__ int scnt[CC];
  __shared__ int total_s, base_s, vc_s;

  int b = blockIdx.x, tid = threadIdx.x;
  for (int i = tid; i < CC * TT; i += 256) {
    float v = det_score[(size_t)b * CC * TT + i];
    kk[i] = (v == -INFINITY) ? 0ull : (((u64)__float_as_uint(v) << 32) | (u32)(~(u32)i));
  }
  if (tid == 0) { total_s = 0; base_s = 0; vc_s = 0; }
  __syncthreads();

  // threshold from per-class top-2 (subset => t <= t100 => superset gathered)
  for (int i = tid; i < 256; i += 256) buf[i] = (i < 2 * CC) ? kk[(i >> 1) * TT + (i & 1)] : 0ull;
  __syncthreads();
  bitonic_desc(buf, 256, tid);
  u64 t = buf[99];
  u64 tq = t ? t : 1ull;          // t==0: fewer than 100 valid in prefix -> gather all valid
  __syncthreads();

  // per-class count of keys >= tq (lists sorted desc)
  if (tid < CC) {
    int lo2 = 0, hi2 = TT;
    while (lo2 < hi2) {
      int mid = (lo2 + hi2) >> 1;
      if (kk[tid * TT + mid] >= tq) lo2 = mid + 1; else hi2 = mid;
    }
    scnt[tid] = lo2;
    atomicAdd(&total_s, lo2);
  }
  __syncthreads();
  int total = total_s;            // >= 100 whenever >=100 valid exist
  int n2 = 128;
  while (n2 < total) n2 <<= 1;    // <= 8192

  // gather per-class prefixes
  if (tid < CC) {
    int m = scnt[tid];
    int gb = atomicAdd(&base_s, m);
    for (int i = 0; i < m; ++i) buf[gb + i] = kk[tid * TT + i];
  }
  __syncthreads();
  for (int i = total + tid; i < n2; i += 256) buf[i] = 0ull;
  __syncthreads();
  bitonic_desc(buf, n2, tid);

  // write outputs
  float* ob = out + (size_t)b * TT * 4;            // [0,3200)
  float* os = out + BB * TT * 4 + (size_t)b * TT;  // [3200,4000)
  float* ol = out + BB * TT * 5 + (size_t)b * TT;  // [4000,4800)
  if (tid < TT) {
    u64 k = buf[tid];
    bool valid = (k != 0ull);
    u32 j = valid ? (u32)(~(u32)k) : 0u;
    float v = __uint_as_float((u32)(k >> 32));
    float4 bx = make_float4(0.f, 0.f, 0.f, 0.f);
    if (valid) bx = *(const float4*)(det_box + ((size_t)b * CC * TT + j) * 4);
    ((float4*)ob)[tid] = bx;
    os[tid] = valid ? v : 0.0f;
    ol[tid] = valid ? (float)(j / TT) : 0.0f;
    if (valid) atomicAdd(&vc_s, 1);
  }
  __syncthreads();
  if (tid == 0) out[BB * TT * 5 + BB * TT + b] = (float)vc_s;
}

// ---------- launch ----------
extern "C" void kernel_launch(void* const* d_in, const int* in_sizes, int n_in,
                              void* d_out, int out_size, void* d_ws, size_t ws_size,
                              hipStream_t stream) {
  const float* boxes  = (const float*)d_in[0];   // (8,16384,4)
  const float* scores = (const float*)d_in[1];   // (8,16384,80)
  float* out = (float*)d_out;                    // 4808 floats

  char* ws = (char*)d_ws;
  u64*   cand      = (u64*)ws;                           // 640*1024*8 = 5,242,880
  float* det_box   = (float*)(ws + 5242880);             // 640*100*16 = 1,024,000
  float* det_score = (float*)(ws + 5242880 + 1024000);   // 640*100*4  =   256,000
  int*   cnt       = (int*)(ws + 5242880 + 1024000 + 256000);          // 2560
  int*   ov        = (int*)(ws + 5242880 + 1024000 + 256000 + 2560);   // 2560

  hipMemsetAsync(cnt, 0, 2 * BB * CC * sizeof(int), stream);
  gather_kernel<<<BB * 32, 256, 0, stream>>>(scores, cand, cnt, ov);
  nms_kernel<<<BB * CC, 256, 0, stream>>>(boxes, scores, cand, cnt, ov, det_score, det_box);
  topk_select<<<BB, 256, 0, stream>>>(det_score, det_box, out);
}